// Round 4
// baseline (183.261 us; speedup 1.0000x reference)
//
#include <hip/hip_runtime.h>

// Problem constants (fixed by setup_inputs): B=8, H=W=512, D=32, K=64
#define B_    8
#define N_    (512 * 512)
#define D_    32
#define K_    64
#define TPB   256
#define NWAVE (TPB / 64)
#define KROW  36                 // row stride (floats): 16B-aligned, spreads banks
#define TABW  (K_ * KROW)        // 2304 floats per wave-private table
#define REC   (K_ * D_ + K_)     // per-block partial record: 2048 sums + 64 counts

struct Lab8 { int l0, l1, l2, l3, l4, l5, l6, l7; };

// ---------------------------------------------------------------------------
// Stage 1: per-block partial segment sums.
// Straight-line duplicate handling: order==0 lanes do a plain float4 RMW and
// bump the count by the whole group size; order>0 lanes (rare, ~4%) issue
// ds_add atomics AFTER the write in program order (same-wave LDS ops are
// processed in order -> race-free). 4-deep global prefetch pipeline.
// ---------------------------------------------------------------------------
__global__ __launch_bounds__(TPB) void seg_partial_kernel(
    const float* __restrict__ emb, const int* __restrict__ lab,
    float* __restrict__ partials, int blk_per_b)
{
    __shared__ __align__(16) float s_tab[NWAVE * TABW];
    __shared__ float s_cnt[NWAVE * K_];

    for (int i = threadIdx.x; i < NWAVE * TABW; i += TPB) s_tab[i] = 0.f;
    for (int i = threadIdx.x; i < NWAVE * K_;  i += TPB) s_cnt[i] = 0.f;
    __syncthreads();

    const int tid  = threadIdx.x;
    const int wave = tid >> 6;
    const int lane = tid & 63;
    const int egl  = lane >> 3;          // element slot within wave: 0..7
    const int d4   = lane & 7;           // float4 slice within element: 0..7
    const int eg   = wave * 8 + egl;     // element slot within block-iter: 0..31

    float* __restrict__ tab = s_tab + wave * TABW;
    float* __restrict__ cnt = s_cnt + wave * K_;

    const int blk = blockIdx.x;
    const int b   = blk / blk_per_b;
    const int bib = blk - b * blk_per_b;
    const long long bbase = (long long)b * N_;
    const float4* __restrict__ embv = reinterpret_cast<const float4*>(emb);
    const int STEP = blk_per_b * 32;
    const int wb = __builtin_amdgcn_readfirstlane(wave * 8);

    auto load_iter = [&](int base, Lab8& L, float4& v) {
        if (base < N_) {                         // uniform branch
            const int* lp = lab + bbase + base + wb;   // wave-uniform -> s_load
            L.l0 = lp[0]; L.l1 = lp[1]; L.l2 = lp[2]; L.l3 = lp[3];
            L.l4 = lp[4]; L.l5 = lp[5]; L.l6 = lp[6]; L.l7 = lp[7];
            v = embv[(bbase + base + eg) * 8 + d4];
        }
    };

    auto process = [&](const Lab8& L, float4 v) {
        // my element's label (cndmask tree over 8 scalar labels)
        int lb = egl < 4 ? (egl < 2 ? (egl == 0 ? L.l0 : L.l1)
                                    : (egl == 2 ? L.l2 : L.l3))
                         : (egl < 6 ? (egl == 4 ? L.l4 : L.l5)
                                    : (egl == 6 ? L.l6 : L.l7));
        const int m0 = (lb == L.l0), m1 = (lb == L.l1), m2 = (lb == L.l2),
                  m3 = (lb == L.l3), m4 = (lb == L.l4), m5 = (lb == L.l5),
                  m6 = (lb == L.l6), m7 = (lb == L.l7);
        const int order = (0 < egl ? m0 : 0) + (1 < egl ? m1 : 0) +
                          (2 < egl ? m2 : 0) + (3 < egl ? m3 : 0) +
                          (4 < egl ? m4 : 0) + (5 < egl ? m5 : 0) +
                          (6 < egl ? m6 : 0);
        const int nsame = m0 + m1 + m2 + m3 + m4 + m5 + m6 + m7;
        const int a = lb * KROW + d4 * 4;
        if (order == 0) {
            float4 cur = *reinterpret_cast<const float4*>(tab + a);
            cur.x += v.x; cur.y += v.y; cur.z += v.z; cur.w += v.w;
            *reinterpret_cast<float4*>(tab + a) = cur;
            if (d4 == 0) cnt[lb] += (float)nsame;
        }
        if (order != 0) {  // rare; issued after the write in program order
            atomicAdd(&tab[a + 0], v.x);
            atomicAdd(&tab[a + 1], v.y);
            atomicAdd(&tab[a + 2], v.z);
            atomicAdd(&tab[a + 3], v.w);
        }
    };

    int base = bib * 32;
    Lab8 A = {}, Bs = {}, Cs = {}, Ds = {};
    float4 va = make_float4(0.f, 0.f, 0.f, 0.f), vb = va, vc = va, vd = va;
    load_iter(base,            A,  va);
    load_iter(base +     STEP, Bs, vb);
    load_iter(base + 2 * STEP, Cs, vc);
    load_iter(base + 3 * STEP, Ds, vd);

    while (base < N_) {
        process(A, va);
        load_iter(base + 4 * STEP, A, va);
        if (base + STEP >= N_) break;
        process(Bs, vb);
        load_iter(base + 5 * STEP, Bs, vb);
        if (base + 2 * STEP >= N_) break;
        process(Cs, vc);
        load_iter(base + 6 * STEP, Cs, vc);
        if (base + 3 * STEP >= N_) break;
        process(Ds, vd);
        load_iter(base + 7 * STEP, Ds, vd);
        base += 4 * STEP;
    }
    __syncthreads();

    // merge the 4 wave tables, write one partial record per block
    float* out = partials + (size_t)blk * REC;
    for (int i = tid; i < K_ * D_; i += TPB) {
        int k = i >> 5, d = i & 31;
        float s = 0.f;
#pragma unroll
        for (int w = 0; w < NWAVE; ++w) s += s_tab[w * TABW + k * KROW + d];
        out[i] = s;
    }
    if (tid < K_) {
        float c = 0.f;
#pragma unroll
        for (int w = 0; w < NWAVE; ++w) c += s_cnt[w * K_ + tid];
        out[K_ * D_ + tid] = c;
    }
}

// ---------------------------------------------------------------------------
// Stage 2: reduce per-block partials into final sums (B,K,D) + counts (B,K).
// unroll 8 keeps 8 strided loads in flight (they hit L2/L3, ~350 cyc each).
// ---------------------------------------------------------------------------
__global__ __launch_bounds__(TPB) void seg_reduce_kernel(
    const float* __restrict__ partials, float* __restrict__ sums_cnts,
    int blk_per_b)
{
    int idx = blockIdx.x * TPB + threadIdx.x;
    if (idx < B_ * K_ * D_) {
        int b = idx / (K_ * D_);
        int r = idx - b * (K_ * D_);
        const float* p = partials + (size_t)b * blk_per_b * REC + r;
        float acc = 0.f;
#pragma unroll 8
        for (int i = 0; i < blk_per_b; ++i) acc += p[(size_t)i * REC];
        sums_cnts[idx] = acc;
    } else if (idx < B_ * K_ * D_ + B_ * K_) {
        int c = idx - B_ * K_ * D_;
        int b = c / K_;
        int k = c - b * K_;
        const float* p = partials + (size_t)b * blk_per_b * REC + K_ * D_ + k;
        float acc = 0.f;
#pragma unroll 8
        for (int i = 0; i < blk_per_b; ++i) acc += p[(size_t)i * REC];
        sums_cnts[idx] = acc;
    }
}

// ---------------------------------------------------------------------------
// Stage 3: one block per batch; transposed float4 centroid table in LDS.
// ---------------------------------------------------------------------------
__global__ __launch_bounds__(TPB) void loss8_kernel(
    const float* __restrict__ sums_cnts, float* __restrict__ batch_loss)
{
    __shared__ __align__(16) float4 s_cent4[8 * K_];  // [j][k]
    __shared__ float s_pres[K_];
    __shared__ float s_wred[NWAVE];

    const int b   = blockIdx.x;
    const int tid = threadIdx.x;
    const float* sums = sums_cnts + (size_t)b * K_ * D_;
    const float* cnts = sums_cnts + (size_t)B_ * K_ * D_ + b * K_;

    for (int i = tid; i < 8 * K_; i += TPB) {
        int j = i >> 6, k = i & 63;
        float inv = 1.0f / fmaxf(cnts[k], 1.0f);
        const float* s = sums + k * D_ + j * 4;
        s_cent4[i] = make_float4(s[0] * inv, s[1] * inv, s[2] * inv, s[3] * inv);
    }
    if (tid < K_) s_pres[tid] = (cnts[tid] > 0.5f) ? 1.f : 0.f;
    __syncthreads();

    const int wave = tid >> 6, lane = tid & 63;

    float4 cb[8];
#pragma unroll
    for (int j = 0; j < 8; ++j) cb[j] = s_cent4[j * K_ + lane];
    const float pres2 = s_pres[lane];

    float acc = 0.f;
#pragma unroll 4
    for (int t = 0; t < 16; ++t) {
        const int k1 = wave * 16 + t;
        float dist = 0.f;
#pragma unroll
        for (int j = 0; j < 8; ++j) {
            float4 a = s_cent4[j * K_ + k1];   // wave-uniform broadcast
            dist += fabsf(a.x - cb[j].x) + fabsf(a.y - cb[j].y)
                  + fabsf(a.z - cb[j].z) + fabsf(a.w - cb[j].w);
        }
        float h = fmaxf(0.25f - dist, 0.f);
        float valid = (k1 < lane) ? s_pres[k1] * pres2 : 0.f;
        acc += valid * h * h;
    }
#pragma unroll
    for (int m = 32; m > 0; m >>= 1) acc += __shfl_xor(acc, m);
    if (lane == 0) s_wred[wave] = acc;
    __syncthreads();
    if (tid == 0) {
        float s = s_wred[0] + s_wred[1] + s_wred[2] + s_wred[3];
        float n = 0.f;
        for (int k = 0; k < K_; ++k) n += s_pres[k];
        float ncomp = n * (n - 1.f) * 0.5f;
        batch_loss[b] = (ncomp > 0.f) ? (s / ncomp) : 0.f;
    }
}

// ---------------------------------------------------------------------------
// Stage 4: average the 8 per-batch losses into out[0].
// ---------------------------------------------------------------------------
__global__ void final_kernel(const float* __restrict__ batch_loss,
                             float* __restrict__ out)
{
    if (threadIdx.x == 0) {
        float t = 0.f;
#pragma unroll
        for (int b = 0; b < B_; ++b) t += batch_loss[b];
        out[0] = t * (1.0f / (float)B_);
    }
}

// ---------------------------------------------------------------------------
extern "C" void kernel_launch(void* const* d_in, const int* in_sizes, int n_in,
                              void* d_out, int out_size, void* d_ws, size_t ws_size,
                              hipStream_t stream)
{
    const float* emb = (const float*)d_in[0];
    const int*   lab = (const int*)d_in[1];
    float*       out = (float*)d_out;
    float*       ws  = (float*)d_ws;

    int blk_per_b = 128;
    const size_t tail_floats = (size_t)(B_ * K_ * D_ + B_ * K_) + B_;
    while (blk_per_b > 1) {
        size_t need = ((size_t)(blk_per_b * B_) * REC + tail_floats) * sizeof(float);
        if (need <= ws_size) break;
        blk_per_b >>= 1;
    }
    const int nblk = blk_per_b * B_;

    float* partials   = ws;
    float* sums_cnts  = ws + (size_t)nblk * REC;
    float* batch_loss = sums_cnts + (size_t)(B_ * K_ * D_ + B_ * K_);

    seg_partial_kernel<<<nblk, TPB, 0, stream>>>(emb, lab, partials, blk_per_b);

    const int tot = B_ * K_ * D_ + B_ * K_;
    seg_reduce_kernel<<<(tot + TPB - 1) / TPB, TPB, 0, stream>>>(
        partials, sums_cnts, blk_per_b);

    loss8_kernel<<<B_, TPB, 0, stream>>>(sums_cnts, batch_loss);

    final_kernel<<<1, 64, 0, stream>>>(batch_loss, out);
}

// Round 5
// 88.366 us; speedup vs baseline: 2.0739x; 2.0739x over previous
//
#include <hip/hip_runtime.h>

// Problem constants (fixed by setup_inputs): B=8, H=W=512, D=32, K=64
#define B_    8
#define N_    (512 * 512)
#define D_    32
#define K_    64
#define TPB   256
#define NWAVE (TPB / 64)
#define KROW  36                 // row stride (floats): 16B-aligned, spreads banks
#define TABW  (K_ * KROW)        // 2304 floats per wave-private table
#define REC   (K_ * D_ + K_)     // per-block partial record: 2048 sums + 64 counts

// ---------------------------------------------------------------------------
// Stage 1: per-block partial segment sums, NO round loop, NO lambdas/structs
// (r4's lambda out-params spilled to scratch: 555 MB HBM writes).
// Straight-line duplicate handling: order==0 lane does the plain float4 RMW
// and adds the whole group's count; order>0 lanes (~4%) issue ds_add atomics
// AFTER the write in program order (same-wave LDS ops complete in issue
// order -> race-free). 1-deep prefetch exactly as the proven r2 kernel.
// ---------------------------------------------------------------------------
__global__ __launch_bounds__(TPB) void seg_partial_kernel(
    const float* __restrict__ emb, const int* __restrict__ lab,
    float* __restrict__ partials, int blk_per_b)
{
    __shared__ __align__(16) float s_tab[NWAVE * TABW];
    __shared__ float s_cnt[NWAVE * K_];

    for (int i = threadIdx.x; i < NWAVE * TABW; i += TPB) s_tab[i] = 0.f;
    for (int i = threadIdx.x; i < NWAVE * K_;  i += TPB) s_cnt[i] = 0.f;
    __syncthreads();

    const int tid  = threadIdx.x;
    const int wave = tid >> 6;
    const int lane = tid & 63;
    const int egl  = lane >> 3;          // element slot within wave: 0..7
    const int d4   = lane & 7;           // float4 slice within element: 0..7
    const int eg   = wave * 8 + egl;     // element slot within block-iter: 0..31

    float* __restrict__ tab = s_tab + wave * TABW;
    float* __restrict__ cnt = s_cnt + wave * K_;

    const int blk = blockIdx.x;
    const int b   = blk / blk_per_b;
    const int bib = blk - b * blk_per_b;
    const long long bbase = (long long)b * N_;
    const float4* __restrict__ embv = reinterpret_cast<const float4*>(emb);
    const int STEP = blk_per_b * 32;
    const int wb = __builtin_amdgcn_readfirstlane(wave * 8);

    int base = bib * 32;
    // prologue loads (iteration 0)
    const int* lp = lab + bbase + base + wb;   // wave-uniform -> scalar loads
    int l0 = lp[0], l1 = lp[1], l2 = lp[2], l3 = lp[3],
        l4 = lp[4], l5 = lp[5], l6 = lp[6], l7 = lp[7];
    float4 v = embv[(bbase + base + eg) * 8 + d4];

    while (base < N_) {
        const int nbase = base + STEP;

        // my element's label (cndmask tree over the 8 scalar labels)
        int lb = egl < 4 ? (egl < 2 ? (egl == 0 ? l0 : l1) : (egl == 2 ? l2 : l3))
                         : (egl < 6 ? (egl == 4 ? l4 : l5) : (egl == 6 ? l6 : l7));

        const int m0 = (lb == l0), m1 = (lb == l1), m2 = (lb == l2),
                  m3 = (lb == l3), m4 = (lb == l4), m5 = (lb == l5),
                  m6 = (lb == l6), m7 = (lb == l7);
        const int order = (0 < egl ? m0 : 0) + (1 < egl ? m1 : 0) +
                          (2 < egl ? m2 : 0) + (3 < egl ? m3 : 0) +
                          (4 < egl ? m4 : 0) + (5 < egl ? m5 : 0) +
                          (6 < egl ? m6 : 0);
        const int nsame = m0 + m1 + m2 + m3 + m4 + m5 + m6 + m7;

        // prefetch next iteration (latency hides under the LDS work)
        int t0 = 0, t1 = 0, t2 = 0, t3 = 0, t4 = 0, t5 = 0, t6 = 0, t7 = 0;
        float4 vn = make_float4(0.f, 0.f, 0.f, 0.f);
        if (nbase < N_) {
            const int* lpn = lab + bbase + nbase + wb;
            t0 = lpn[0]; t1 = lpn[1]; t2 = lpn[2]; t3 = lpn[3];
            t4 = lpn[4]; t5 = lpn[5]; t6 = lpn[6]; t7 = lpn[7];
            vn = embv[(bbase + nbase + eg) * 8 + d4];
        }

        const int a = lb * KROW + d4 * 4;
        if (order == 0) {
            float4 cur = *reinterpret_cast<const float4*>(tab + a);
            cur.x += v.x; cur.y += v.y; cur.z += v.z; cur.w += v.w;
            *reinterpret_cast<float4*>(tab + a) = cur;
            if (d4 == 0) cnt[lb] += (float)nsame;
        } else {  // rare (~4% of lanes); lands after the write in issue order
            atomicAdd(&tab[a + 0], v.x);
            atomicAdd(&tab[a + 1], v.y);
            atomicAdd(&tab[a + 2], v.z);
            atomicAdd(&tab[a + 3], v.w);
        }

        base = nbase;
        l0 = t0; l1 = t1; l2 = t2; l3 = t3;
        l4 = t4; l5 = t5; l6 = t6; l7 = t7;
        v = vn;
    }
    __syncthreads();

    // merge the 4 wave tables, write one partial record per block
    float* out = partials + (size_t)blk * REC;
    for (int i = tid; i < K_ * D_; i += TPB) {
        int k = i >> 5, d = i & 31;
        float s = 0.f;
#pragma unroll
        for (int w = 0; w < NWAVE; ++w) s += s_tab[w * TABW + k * KROW + d];
        out[i] = s;
    }
    if (tid < K_) {
        float c = 0.f;
#pragma unroll
        for (int w = 0; w < NWAVE; ++w) c += s_cnt[w * K_ + tid];
        out[K_ * D_ + tid] = c;
    }
}

// ---------------------------------------------------------------------------
// Stage 2: reduce per-block partials into final sums (B,K,D) + counts (B,K).
// unroll 8 keeps 8 strided loads in flight (L2/L3 latency-bound otherwise).
// ---------------------------------------------------------------------------
__global__ __launch_bounds__(TPB) void seg_reduce_kernel(
    const float* __restrict__ partials, float* __restrict__ sums_cnts,
    int blk_per_b)
{
    int idx = blockIdx.x * TPB + threadIdx.x;
    if (idx < B_ * K_ * D_) {
        int b = idx / (K_ * D_);
        int r = idx - b * (K_ * D_);
        const float* p = partials + (size_t)b * blk_per_b * REC + r;
        float acc = 0.f;
#pragma unroll 8
        for (int i = 0; i < blk_per_b; ++i) acc += p[(size_t)i * REC];
        sums_cnts[idx] = acc;
    } else if (idx < B_ * K_ * D_ + B_ * K_) {
        int c = idx - B_ * K_ * D_;
        int b = c / K_;
        int k = c - b * K_;
        const float* p = partials + (size_t)b * blk_per_b * REC + K_ * D_ + k;
        float acc = 0.f;
#pragma unroll 8
        for (int i = 0; i < blk_per_b; ++i) acc += p[(size_t)i * REC];
        sums_cnts[idx] = acc;
    }
}

// ---------------------------------------------------------------------------
// Stage 3: one block per batch; transposed float4 centroid table in LDS.
// ---------------------------------------------------------------------------
__global__ __launch_bounds__(TPB) void loss8_kernel(
    const float* __restrict__ sums_cnts, float* __restrict__ batch_loss)
{
    __shared__ __align__(16) float4 s_cent4[8 * K_];  // [j][k]
    __shared__ float s_pres[K_];
    __shared__ float s_wred[NWAVE];

    const int b   = blockIdx.x;
    const int tid = threadIdx.x;
    const float* sums = sums_cnts + (size_t)b * K_ * D_;
    const float* cnts = sums_cnts + (size_t)B_ * K_ * D_ + b * K_;

    for (int i = tid; i < 8 * K_; i += TPB) {
        int j = i >> 6, k = i & 63;
        float inv = 1.0f / fmaxf(cnts[k], 1.0f);
        const float* s = sums + k * D_ + j * 4;
        s_cent4[i] = make_float4(s[0] * inv, s[1] * inv, s[2] * inv, s[3] * inv);
    }
    if (tid < K_) s_pres[tid] = (cnts[tid] > 0.5f) ? 1.f : 0.f;
    __syncthreads();

    const int wave = tid >> 6, lane = tid & 63;

    float4 cb[8];
#pragma unroll
    for (int j = 0; j < 8; ++j) cb[j] = s_cent4[j * K_ + lane];
    const float pres2 = s_pres[lane];

    float acc = 0.f;
#pragma unroll 4
    for (int t = 0; t < 16; ++t) {
        const int k1 = wave * 16 + t;
        float dist = 0.f;
#pragma unroll
        for (int j = 0; j < 8; ++j) {
            float4 a = s_cent4[j * K_ + k1];   // wave-uniform broadcast
            dist += fabsf(a.x - cb[j].x) + fabsf(a.y - cb[j].y)
                  + fabsf(a.z - cb[j].z) + fabsf(a.w - cb[j].w);
        }
        float h = fmaxf(0.25f - dist, 0.f);
        float valid = (k1 < lane) ? s_pres[k1] * pres2 : 0.f;
        acc += valid * h * h;
    }
#pragma unroll
    for (int m = 32; m > 0; m >>= 1) acc += __shfl_xor(acc, m);
    if (lane == 0) s_wred[wave] = acc;
    __syncthreads();
    if (tid == 0) {
        float s = s_wred[0] + s_wred[1] + s_wred[2] + s_wred[3];
        float n = 0.f;
        for (int k = 0; k < K_; ++k) n += s_pres[k];
        float ncomp = n * (n - 1.f) * 0.5f;
        batch_loss[b] = (ncomp > 0.f) ? (s / ncomp) : 0.f;
    }
}

// ---------------------------------------------------------------------------
// Stage 4: average the 8 per-batch losses into out[0].
// ---------------------------------------------------------------------------
__global__ void final_kernel(const float* __restrict__ batch_loss,
                             float* __restrict__ out)
{
    if (threadIdx.x == 0) {
        float t = 0.f;
#pragma unroll
        for (int b = 0; b < B_; ++b) t += batch_loss[b];
        out[0] = t * (1.0f / (float)B_);
    }
}

// ---------------------------------------------------------------------------
extern "C" void kernel_launch(void* const* d_in, const int* in_sizes, int n_in,
                              void* d_out, int out_size, void* d_ws, size_t ws_size,
                              hipStream_t stream)
{
    const float* emb = (const float*)d_in[0];
    const int*   lab = (const int*)d_in[1];
    float*       out = (float*)d_out;
    float*       ws  = (float*)d_ws;

    int blk_per_b = 128;
    const size_t tail_floats = (size_t)(B_ * K_ * D_ + B_ * K_) + B_;
    while (blk_per_b > 1) {
        size_t need = ((size_t)(blk_per_b * B_) * REC + tail_floats) * sizeof(float);
        if (need <= ws_size) break;
        blk_per_b >>= 1;
    }
    const int nblk = blk_per_b * B_;

    float* partials   = ws;
    float* sums_cnts  = ws + (size_t)nblk * REC;
    float* batch_loss = sums_cnts + (size_t)(B_ * K_ * D_ + B_ * K_);

    seg_partial_kernel<<<nblk, TPB, 0, stream>>>(emb, lab, partials, blk_per_b);

    const int tot = B_ * K_ * D_ + B_ * K_;
    seg_reduce_kernel<<<(tot + TPB - 1) / TPB, TPB, 0, stream>>>(
        partials, sums_cnts, blk_per_b);

    loss8_kernel<<<B_, TPB, 0, stream>>>(sums_cnts, batch_loss);

    final_kernel<<<1, 64, 0, stream>>>(batch_loss, out);
}

// Round 6
// 76.569 us; speedup vs baseline: 2.3934x; 1.1541x over previous
//
#include <hip/hip_runtime.h>

// Problem constants (fixed by setup_inputs): B=8, H=W=512, D=32, K=64
#define B_    8
#define N_    (512 * 512)
#define D_    32
#define K_    64
#define TPB   256
#define NWAVE (TPB / 64)
#define KROW  36                 // row stride (floats): 16B-aligned, spreads banks
#define TABW  (K_ * KROW)        // 2304 floats per wave-private table
#define REC   (K_ * D_ + K_)     // per-block partial record: 2048 sums + 64 counts

// ---------------------------------------------------------------------------
// Stage 1: per-block partial segment sums. Straight-line duplicate handling
// (proven r5) + 2-deep software pipeline via macro-expanded NAMED registers
// (r4's lambda out-params went to scratch: 555 MB HBM writes — never again).
// order==0 lane does the plain float4 RMW and adds the whole group's count;
// order>0 lanes (~4%) issue ds_add atomics AFTER the write in program order
// (same-wave LDS ops complete in issue order -> race-free).
// ---------------------------------------------------------------------------

// Process one iteration's registers, refilling them from PBASE (2 iters ahead).
#define PROC(L0,L1,L2,L3,L4,L5,L6,L7, V, PBASE)                               \
  {                                                                           \
    int lb = egl < 4 ? (egl < 2 ? (egl == 0 ? L0 : L1)                        \
                                : (egl == 2 ? L2 : L3))                       \
                     : (egl < 6 ? (egl == 4 ? L4 : L5)                        \
                                : (egl == 6 ? L6 : L7));                      \
    const int m0 = (lb == L0), m1 = (lb == L1), m2 = (lb == L2),              \
              m3 = (lb == L3), m4 = (lb == L4), m5 = (lb == L5),              \
              m6 = (lb == L6), m7 = (lb == L7);                               \
    const int order = (g0 & m0) + (g1 & m1) + (g2 & m2) + (g3 & m3) +         \
                      (g4 & m4) + (g5 & m5) + (g6 & m6);                      \
    const int nsame = m0 + m1 + m2 + m3 + m4 + m5 + m6 + m7;                  \
    const float4 vc = V;                                                      \
    const int pb = (PBASE);                                                   \
    if (pb < N_) {        /* uniform branch */                                \
      const int* lp = lab + bbase + pb + wb;   /* wave-uniform -> s_load */   \
      L0 = lp[0]; L1 = lp[1]; L2 = lp[2]; L3 = lp[3];                         \
      L4 = lp[4]; L5 = lp[5]; L6 = lp[6]; L7 = lp[7];                         \
      V = embv[(bbase + pb + eg) * 8 + d4];                                   \
    }                                                                         \
    const int a = lb * KROW + d4 * 4;                                         \
    if (order == 0) {                                                         \
      float4 cur = *reinterpret_cast<const float4*>(tab + a);                 \
      cur.x += vc.x; cur.y += vc.y; cur.z += vc.z; cur.w += vc.w;             \
      *reinterpret_cast<float4*>(tab + a) = cur;                              \
      if (d4 == 0) cnt[lb] += (float)nsame;                                   \
    } else {  /* rare; lands after the write in issue order */                \
      atomicAdd(&tab[a + 0], vc.x);                                           \
      atomicAdd(&tab[a + 1], vc.y);                                           \
      atomicAdd(&tab[a + 2], vc.z);                                           \
      atomicAdd(&tab[a + 3], vc.w);                                           \
    }                                                                         \
  }

__global__ __launch_bounds__(TPB) void seg_partial_kernel(
    const float* __restrict__ emb, const int* __restrict__ lab,
    float* __restrict__ partials, int blk_per_b)
{
    __shared__ __align__(16) float s_tab[NWAVE * TABW];
    __shared__ float s_cnt[NWAVE * K_];

    for (int i = threadIdx.x; i < NWAVE * TABW; i += TPB) s_tab[i] = 0.f;
    for (int i = threadIdx.x; i < NWAVE * K_;  i += TPB) s_cnt[i] = 0.f;
    __syncthreads();

    const int tid  = threadIdx.x;
    const int wave = tid >> 6;
    const int lane = tid & 63;
    const int egl  = lane >> 3;          // element slot within wave: 0..7
    const int d4   = lane & 7;           // float4 slice within element: 0..7
    const int eg   = wave * 8 + egl;     // element slot within block-iter: 0..31

    // loop-invariant "slot i is earlier than mine" predicates
    const int g0 = (0 < egl), g1 = (1 < egl), g2 = (2 < egl), g3 = (3 < egl),
              g4 = (4 < egl), g5 = (5 < egl), g6 = (6 < egl);

    float* __restrict__ tab = s_tab + wave * TABW;
    float* __restrict__ cnt = s_cnt + wave * K_;

    const int blk = blockIdx.x;
    const int b   = blk / blk_per_b;
    const int bib = blk - b * blk_per_b;
    const long long bbase = (long long)b * N_;
    const float4* __restrict__ embv = reinterpret_cast<const float4*>(emb);
    const int STEP = blk_per_b * 32;
    const int wb = __builtin_amdgcn_readfirstlane(wave * 8);

    int ib = bib * 32;

    // prologue: fill both pipeline stages (A @ ib, B @ ib+STEP)
    int a0, a1, a2, a3, a4, a5, a6, a7;
    float4 va;
    {
        const int* lp = lab + bbase + ib + wb;
        a0 = lp[0]; a1 = lp[1]; a2 = lp[2]; a3 = lp[3];
        a4 = lp[4]; a5 = lp[5]; a6 = lp[6]; a7 = lp[7];
        va = embv[(bbase + ib + eg) * 8 + d4];
    }
    int b0 = 0, b1 = 0, b2 = 0, b3 = 0, b4 = 0, b5 = 0, b6 = 0, b7 = 0;
    float4 vb = make_float4(0.f, 0.f, 0.f, 0.f);
    if (ib + STEP < N_) {
        const int* lp = lab + bbase + ib + STEP + wb;
        b0 = lp[0]; b1 = lp[1]; b2 = lp[2]; b3 = lp[3];
        b4 = lp[4]; b5 = lp[5]; b6 = lp[6]; b7 = lp[7];
        vb = embv[(bbase + ib + STEP + eg) * 8 + d4];
    }

    for (;;) {
        PROC(a0, a1, a2, a3, a4, a5, a6, a7, va, ib + 2 * STEP);
        ib += STEP;
        if (ib >= N_) break;
        PROC(b0, b1, b2, b3, b4, b5, b6, b7, vb, ib + 2 * STEP);
        ib += STEP;
        if (ib >= N_) break;
    }
    __syncthreads();

    // merge the 4 wave tables, write one partial record per block
    float* out = partials + (size_t)blk * REC;
    for (int i = tid; i < K_ * D_; i += TPB) {
        int k = i >> 5, d = i & 31;
        float s = 0.f;
#pragma unroll
        for (int w = 0; w < NWAVE; ++w) s += s_tab[w * TABW + k * KROW + d];
        out[i] = s;
    }
    if (tid < K_) {
        float c = 0.f;
#pragma unroll
        for (int w = 0; w < NWAVE; ++w) c += s_cnt[w * K_ + tid];
        out[K_ * D_ + tid] = c;
    }
}

// ---------------------------------------------------------------------------
// Stage 2: reduce per-block partials into final sums (B,K,D) + counts (B,K).
// Each thread reduces 4 consecutive positions with float4 loads: a wave reads
// 1 KB contiguous per record step (full coalescing rate).
// ---------------------------------------------------------------------------
#define NS4 (B_ * K_ * D_ / 4)   // 4096 sum-quads
#define NC4 (B_ * K_ / 4)        // 128 count-quads

__global__ __launch_bounds__(TPB) void seg_reduce_kernel(
    const float* __restrict__ partials, float* __restrict__ sums_cnts,
    int blk_per_b)
{
    int idx = blockIdx.x * TPB + threadIdx.x;
    if (idx < NS4) {
        int b  = idx / (K_ * D_ / 4);
        int r4 = idx - b * (K_ * D_ / 4);
        const float* p = partials + (size_t)b * blk_per_b * REC + r4 * 4;
        float4 acc = make_float4(0.f, 0.f, 0.f, 0.f);
#pragma unroll 8
        for (int i = 0; i < blk_per_b; ++i) {
            float4 v = *reinterpret_cast<const float4*>(p + (size_t)i * REC);
            acc.x += v.x; acc.y += v.y; acc.z += v.z; acc.w += v.w;
        }
        *reinterpret_cast<float4*>(sums_cnts + (size_t)b * K_ * D_ + r4 * 4) = acc;
    } else if (idx < NS4 + NC4) {
        int c4 = idx - NS4;
        int b  = c4 / (K_ / 4);
        int k4 = c4 - b * (K_ / 4);
        const float* p = partials + (size_t)b * blk_per_b * REC + K_ * D_ + k4 * 4;
        float4 acc = make_float4(0.f, 0.f, 0.f, 0.f);
#pragma unroll 8
        for (int i = 0; i < blk_per_b; ++i) {
            float4 v = *reinterpret_cast<const float4*>(p + (size_t)i * REC);
            acc.x += v.x; acc.y += v.y; acc.z += v.z; acc.w += v.w;
        }
        *reinterpret_cast<float4*>(
            sums_cnts + (size_t)B_ * K_ * D_ + b * K_ + k4 * 4) = acc;
    }
}

// ---------------------------------------------------------------------------
// Stage 3: one block per batch; transposed float4 centroid table in LDS.
// ---------------------------------------------------------------------------
__global__ __launch_bounds__(TPB) void loss8_kernel(
    const float* __restrict__ sums_cnts, float* __restrict__ batch_loss)
{
    __shared__ __align__(16) float4 s_cent4[8 * K_];  // [j][k]
    __shared__ float s_pres[K_];
    __shared__ float s_wred[NWAVE];

    const int b   = blockIdx.x;
    const int tid = threadIdx.x;
    const float* sums = sums_cnts + (size_t)b * K_ * D_;
    const float* cnts = sums_cnts + (size_t)B_ * K_ * D_ + b * K_;

    for (int i = tid; i < 8 * K_; i += TPB) {
        int j = i >> 6, k = i & 63;
        float inv = 1.0f / fmaxf(cnts[k], 1.0f);
        const float* s = sums + k * D_ + j * 4;
        s_cent4[i] = make_float4(s[0] * inv, s[1] * inv, s[2] * inv, s[3] * inv);
    }
    if (tid < K_) s_pres[tid] = (cnts[tid] > 0.5f) ? 1.f : 0.f;
    __syncthreads();

    const int wave = tid >> 6, lane = tid & 63;

    float4 cb[8];
#pragma unroll
    for (int j = 0; j < 8; ++j) cb[j] = s_cent4[j * K_ + lane];
    const float pres2 = s_pres[lane];

    float acc = 0.f;
#pragma unroll 4
    for (int t = 0; t < 16; ++t) {
        const int k1 = wave * 16 + t;
        float dist = 0.f;
#pragma unroll
        for (int j = 0; j < 8; ++j) {
            float4 a = s_cent4[j * K_ + k1];   // wave-uniform broadcast
            dist += fabsf(a.x - cb[j].x) + fabsf(a.y - cb[j].y)
                  + fabsf(a.z - cb[j].z) + fabsf(a.w - cb[j].w);
        }
        float h = fmaxf(0.25f - dist, 0.f);
        float valid = (k1 < lane) ? s_pres[k1] * pres2 : 0.f;
        acc += valid * h * h;
    }
#pragma unroll
    for (int m = 32; m > 0; m >>= 1) acc += __shfl_xor(acc, m);
    if (lane == 0) s_wred[wave] = acc;
    __syncthreads();
    if (tid == 0) {
        float s = s_wred[0] + s_wred[1] + s_wred[2] + s_wred[3];
        float n = 0.f;
        for (int k = 0; k < K_; ++k) n += s_pres[k];
        float ncomp = n * (n - 1.f) * 0.5f;
        batch_loss[b] = (ncomp > 0.f) ? (s / ncomp) : 0.f;
    }
}

// ---------------------------------------------------------------------------
// Stage 4: average the 8 per-batch losses into out[0].
// ---------------------------------------------------------------------------
__global__ void final_kernel(const float* __restrict__ batch_loss,
                             float* __restrict__ out)
{
    if (threadIdx.x == 0) {
        float t = 0.f;
#pragma unroll
        for (int b = 0; b < B_; ++b) t += batch_loss[b];
        out[0] = t * (1.0f / (float)B_);
    }
}

// ---------------------------------------------------------------------------
extern "C" void kernel_launch(void* const* d_in, const int* in_sizes, int n_in,
                              void* d_out, int out_size, void* d_ws, size_t ws_size,
                              hipStream_t stream)
{
    const float* emb = (const float*)d_in[0];
    const int*   lab = (const int*)d_in[1];
    float*       out = (float*)d_out;
    float*       ws  = (float*)d_ws;

    int blk_per_b = 128;
    const size_t tail_floats = (size_t)(B_ * K_ * D_ + B_ * K_) + B_;
    while (blk_per_b > 1) {
        size_t need = ((size_t)(blk_per_b * B_) * REC + tail_floats) * sizeof(float);
        if (need <= ws_size) break;
        blk_per_b >>= 1;
    }
    const int nblk = blk_per_b * B_;

    float* partials   = ws;
    float* sums_cnts  = ws + (size_t)nblk * REC;
    float* batch_loss = sums_cnts + (size_t)(B_ * K_ * D_ + B_ * K_);

    seg_partial_kernel<<<nblk, TPB, 0, stream>>>(emb, lab, partials, blk_per_b);

    const int tot4 = NS4 + NC4;
    seg_reduce_kernel<<<(tot4 + TPB - 1) / TPB, TPB, 0, stream>>>(
        partials, sums_cnts, blk_per_b);

    loss8_kernel<<<B_, TPB, 0, stream>>>(sums_cnts, batch_loss);

    final_kernel<<<1, 64, 0, stream>>>(batch_loss, out);
}